// Round 7
// baseline (487.186 us; speedup 1.0000x reference)
//
#include <hip/hip_runtime.h>
#include <stdint.h>

#define N 8192
#define IN_F 512
#define OUT_F 128
#define NCLS 10
#define ALPHA 0.2f

#define WCOLS 1024          // j-window per split group
#define NSP (N / WCOLS)     // 8 split groups
#define BK 128              // j per inner iteration
#define NIT (WCOLS / BK)    // 8 iterations

typedef float f32x4 __attribute__((ext_vector_type(4)));
typedef int   i32x4 __attribute__((ext_vector_type(4)));
typedef unsigned u32x4 __attribute__((ext_vector_type(4)));
typedef short s16x8 __attribute__((ext_vector_type(8)));

__device__ __forceinline__ short f2bf(float x) {
    unsigned u = __builtin_bit_cast(unsigned, x);
    u = (u + 0x7FFFu + ((u >> 16) & 1u)) >> 16;  // RNE
    return (short)u;
}
__device__ __forceinline__ float bf2f(short s) {
    unsigned u = ((unsigned)(unsigned short)s) << 16;
    return __builtin_bit_cast(float, u);
}

// ---------------------------------------------------------------------------
// Kernel P: PACK — memcpy-shaped dist>0 -> 1-bit mask (256 MB -> 8 MB).
// 2048 blocks x 256 thr = 32 waves/CU, ~24 VGPRs, no LDS, no cross-lane ops.
// Lane l packs j = l*8..l*8+7 of its row-chunk into ONE BYTE (two i32x4
// loads, 7 VALU ops, one u8 store). Per-wave reads are linear; stores are
// 64 B contiguous per instruction. This is the harness-fill (6.7 TB/s)
// pattern — streaming decoupled from all consumption.
// mask8[row*1024 + (j>>3)] bit (j&7) = dist[row][j] > 0.
// ---------------------------------------------------------------------------
__global__ __launch_bounds__(256)
void pack_kernel(const int* __restrict__ dist, unsigned char* __restrict__ mask8) {
    const int t = threadIdx.x;
    const int row = blockIdx.x * 4 + (t >> 6);     // 4 rows per block
    const int l = t & 63;
    const int* __restrict__ rp = dist + (size_t)row * N;
    unsigned char* __restrict__ mp = mask8 + (size_t)row * (N / 8);

    #pragma unroll 4
    for (int c = 0; c < 16; ++c) {                 // 16 chunks of 512 ints
        const int jb = c * 512 + l * 8;
        i32x4 v0 = *(const i32x4*)(rp + jb);
        i32x4 v1 = *(const i32x4*)(rp + jb + 4);
        unsigned b = (unsigned)(v0[0] > 0)       | ((unsigned)(v0[1] > 0) << 1)
                   | ((unsigned)(v0[2] > 0) << 2) | ((unsigned)(v0[3] > 0) << 3)
                   | ((unsigned)(v1[0] > 0) << 4) | ((unsigned)(v1[1] > 0) << 5)
                   | ((unsigned)(v1[2] > 0) << 6) | ((unsigned)(v1[3] > 0) << 7);
        mp[c * 64 + l] = (unsigned char)b;
    }
}

// ---------------------------------------------------------------------------
// Kernel 0: split W [512][128] fp32 -> bf16 hi/lo, fragment-blocked:
// idx(col,k) = (k>>5)*(128*32) + col*32 + (k&31)
// ---------------------------------------------------------------------------
__global__ void split_w_kernel(const float* __restrict__ W,
                               short* __restrict__ WThi, short* __restrict__ WTlo) {
    int idx = blockIdx.x * 256 + threadIdx.x;       // 512*128 = 65536
    int k = idx >> 7, col = idx & 127;
    float x = W[idx];
    short hi = f2bf(x);
    short lo = f2bf(x - bf2f(hi));
    size_t a = (size_t)(k >> 5) * (128 * 32) + (size_t)col * 32 + (k & 31);
    WThi[a] = hi;
    WTlo[a] = lo;
}

// ---------------------------------------------------------------------------
// Kernel 1: Wh = h@W via split-bf16 MFMA (~fp32 accuracy). Writes Wh1/Wh2
// (fp32) and WhT bf16 fragment-blocked [(j>>5)][col][j&31].
// ---------------------------------------------------------------------------
#define WH_ROWS 16
#define WH_STR 520

__global__ __launch_bounds__(256, 2)
void wh_kernel(const float* __restrict__ h, const short* __restrict__ WThi,
               const short* __restrict__ WTlo, const float* __restrict__ a,
               short* __restrict__ WhT, float* __restrict__ Wh1,
               float* __restrict__ Wh2) {
    __shared__ __align__(16) short Ahi[WH_ROWS][WH_STR];
    __shared__ __align__(16) short Alo[WH_ROWS][WH_STR];
    __shared__ __align__(16) float whs[WH_ROWS][OUT_F + 4];

    const int t = threadIdx.x;
    const int r0 = blockIdx.x * WH_ROWS;

    {   // stage h tile [16][512] as bf16 hi/lo
        int row = t >> 4, c4 = t & 15;
        const float* hrow = h + (size_t)(r0 + row) * IN_F;
        #pragma unroll
        for (int jj = 0; jj < 4; ++jj) {
            int k0 = c4 * 8 + jj * 128;
            f32x4 x0 = *(const f32x4*)(hrow + k0);
            f32x4 x1 = *(const f32x4*)(hrow + k0 + 4);
            s16x8 hi, lo;
            #pragma unroll
            for (int e = 0; e < 4; ++e) {
                short h0 = f2bf(x0[e]); hi[e] = h0; lo[e] = f2bf(x0[e] - bf2f(h0));
                short h1 = f2bf(x1[e]); hi[4 + e] = h1; lo[4 + e] = f2bf(x1[e] - bf2f(h1));
            }
            *(s16x8*)&Ahi[row][k0] = hi;
            *(s16x8*)&Alo[row][k0] = lo;
        }
    }
    __syncthreads();

    const int lane = t & 63, w = t >> 6;
    const int q = lane >> 4, ln16 = lane & 15;
    f32x4 acc[2] = {};
    #pragma unroll
    for (int kc = 0; kc < IN_F / 32; ++kc) {
        s16x8 ahi = *(const s16x8*)&Ahi[ln16][kc * 32 + q * 8];
        s16x8 alo = *(const s16x8*)&Alo[ln16][kc * 32 + q * 8];
        #pragma unroll
        for (int nt = 0; nt < 2; ++nt) {
            int col = w * 32 + nt * 16 + ln16;
            size_t boff = (size_t)kc * 4096 + (size_t)col * 32 + q * 8;
            s16x8 bhi = *(const s16x8*)(WThi + boff);
            s16x8 blo = *(const s16x8*)(WTlo + boff);
            acc[nt] = __builtin_amdgcn_mfma_f32_16x16x32_bf16(ahi, bhi, acc[nt], 0, 0, 0);
            acc[nt] = __builtin_amdgcn_mfma_f32_16x16x32_bf16(ahi, blo, acc[nt], 0, 0, 0);
            acc[nt] = __builtin_amdgcn_mfma_f32_16x16x32_bf16(alo, bhi, acc[nt], 0, 0, 0);
        }
    }
    #pragma unroll
    for (int nt = 0; nt < 2; ++nt)
        #pragma unroll
        for (int reg = 0; reg < 4; ++reg)
            whs[q * 4 + reg][w * 32 + nt * 16 + ln16] = acc[nt][reg];
    __syncthreads();

    if (t < 128) {
        int r = t >> 3, s = t & 7;
        float s1 = 0.f, s2 = 0.f;
        #pragma unroll
        for (int cc = 0; cc < 16; ++cc) {
            int c = s * 16 + cc;
            float v = whs[r][c];
            s1 = fmaf(v, a[c], s1);
            s2 = fmaf(v, a[OUT_F + c], s2);
        }
        s1 += __shfl_xor(s1, 1); s1 += __shfl_xor(s1, 2); s1 += __shfl_xor(s1, 4);
        s2 += __shfl_xor(s2, 1); s2 += __shfl_xor(s2, 2); s2 += __shfl_xor(s2, 4);
        if (s == 0) { Wh1[r0 + r] = s1; Wh2[r0 + r] = s2; }
    }

    {   // WhT bf16 fragment-blocked write
        int c = t >> 1, h8 = t & 1;
        s16x8 pack;
        #pragma unroll
        for (int rr = 0; rr < 8; ++rr) pack[rr] = f2bf(whs[h8 * 8 + rr][c]);
        size_t addr = (size_t)(r0 >> 5) * 4096 + (size_t)c * 32 + (r0 & 16) + h8 * 8;
        *(s16x8*)(WhT + addr) = pack;
    }
}

// ---------------------------------------------------------------------------
// Kernel 2: fused attention consuming the PREPACKED mask (L3-resident 8 MB)
// — zero HBM dependence in the hot loop. Block = 4 waves, 32 rows x 1024-j
// window. Wave pair (rh = w>>1) owns 16 rows; within a pair, nh = w&1 takes
// 64 of the 128 output cols (acc[4] = 16 regs -> high occupancy). P-phase
// lane map == MFMA A-operand layout; exp computed redundantly by the two
// nh-waves (VALU is cheap). Partials to workspace; grid = 256 i-tiles x 8 sp.
// ---------------------------------------------------------------------------
__global__ __launch_bounds__(256, 6)
void attn_kernel(const unsigned* __restrict__ mask32, const short* __restrict__ WhT,
                 const float* __restrict__ Wh1v, const float* __restrict__ Wh2v,
                 float* __restrict__ acc_part, float* __restrict__ l_part) {
    __shared__ unsigned maskW[32][33];               // 32 rows x 32 words (+1 pad)
    __shared__ __align__(16) float wh2L[WCOLS];

    const int t = threadIdx.x;
    const int it = blockIdx.x & 255;                 // 256 i-tiles of 32 rows
    const int sp = blockIdx.x >> 8;
    const int i0 = it * 32;
    const int j0 = sp * WCOLS;
    const int lane = t & 63, w = t >> 6;
    const int q = lane >> 4, m = lane & 15;
    const int rh = w >> 1, nh = w & 1;

    // ---- stage mask slice (32 rows x 32 u32) + Wh2 window into LDS
    #pragma unroll
    for (int ii = 0; ii < 4; ++ii) {
        int idx = t + ii * 256;                      // 1024 words
        int r = idx >> 5, wq = idx & 31;
        maskW[r][wq] = mask32[(size_t)(i0 + r) * (N / 32) + (j0 >> 5) + wq];
    }
    *(f32x4*)&wh2L[t * 4] = *(const f32x4*)(Wh2v + j0 + t * 4);
    __syncthreads();

    // ---- flash loop from LDS/L2
    const int rowm = rh * 16 + m;                    // A-row this lane holds
    const float wh1 = Wh1v[i0 + rowm];
    float l_acc = 0.f;
    f32x4 acc[4] = {};                               // 16 rows x 64 cols per wave

    for (int kt = 0; kt < NIT; ++kt) {
        const int jb = kt * BK;
        s16x8 afr[4];
        #pragma unroll
        for (int kc = 0; kc < 4; ++kc) {
            unsigned mw = maskW[rowm][(jb >> 5) + kc];   // stride-33: conflict-free
            unsigned byq = (mw >> (q * 8)) & 255u;       // this lane's 8 j-bits
            f32x4 w20 = *(const f32x4*)&wh2L[jb + kc * 32 + q * 8];
            f32x4 w21 = *(const f32x4*)&wh2L[jb + kc * 32 + q * 8 + 4];
            #pragma unroll
            for (int e = 0; e < 4; ++e) {
                float sv = wh1 + w20[e];
                float lr = fmaxf(sv, ALPHA * sv);
                float pv = ((byq >> e) & 1u) ? __expf(lr) : 0.f;
                l_acc += pv;
                afr[kc][e] = (short)((__builtin_bit_cast(unsigned, pv) + 0x8000u) >> 16);
                float sv1 = wh1 + w21[e];
                float lr1 = fmaxf(sv1, ALPHA * sv1);
                float pv1 = ((byq >> (4 + e)) & 1u) ? __expf(lr1) : 0.f;
                l_acc += pv1;
                afr[kc][4 + e] = (short)((__builtin_bit_cast(unsigned, pv1) + 0x8000u) >> 16);
            }
        }
        const short* bb = WhT + (size_t)((j0 + jb) >> 5) * 4096 + q * 8;
        #pragma unroll
        for (int kc = 0; kc < 4; ++kc) {
            const short* bkc = bb + (size_t)kc * 4096;
            #pragma unroll
            for (int nt = 0; nt < 4; ++nt) {
                s16x8 bfr = *(const s16x8*)(bkc + (nh * 64 + nt * 16 + m) * 32);
                acc[nt] = __builtin_amdgcn_mfma_f32_16x16x32_bf16(afr[kc], bfr, acc[nt], 0, 0, 0);
            }
        }
    }

    // row-sum over the 4 q-slices (lanes m, m+16, m+32, m+48)
    l_acc += __shfl_xor(l_acc, 16);
    l_acc += __shfl_xor(l_acc, 32);
    if (q == 0 && nh == 0) l_part[(size_t)sp * N + i0 + rowm] = l_acc;

    // partials: out row = i0 + rh*16 + q*4 + reg, col = nh*64 + nt*16 + m
    float* ap = acc_part + (size_t)sp * N * OUT_F
              + ((size_t)i0 + rh * 16 + q * 4) * OUT_F + nh * 64 + m;
    #pragma unroll
    for (int reg = 0; reg < 4; ++reg)
        #pragma unroll
        for (int nt = 0; nt < 4; ++nt)
            ap[(size_t)reg * OUT_F + nt * 16] = acc[nt][reg];
}

// ---------------------------------------------------------------------------
// Kernel 3: reduce partials, softmax-divide, elu, classifier.
// ---------------------------------------------------------------------------
__global__ __launch_bounds__(256, 4)
void reduce_kernel(const float* __restrict__ acc_part, const float* __restrict__ l_part,
                   const float* __restrict__ Wc, const float* __restrict__ bcv,
                   float* __restrict__ out) {
    __shared__ __align__(16) float hu[16][OUT_F + 4];
    const int t = threadIdx.x;
    const int i0 = blockIdx.x * 16;
    const int row = t >> 4, cg = t & 15;

    f32x4 v0 = {0.f, 0.f, 0.f, 0.f}, v1 = {0.f, 0.f, 0.f, 0.f};
    float l = 0.f;
    for (int s = 0; s < NSP; ++s) {
        const float* ap = acc_part + (size_t)s * N * OUT_F + (size_t)(i0 + row) * OUT_F + cg * 8;
        v0 += *(const f32x4*)ap;
        v1 += *(const f32x4*)(ap + 4);
        l += l_part[(size_t)s * N + i0 + row];
    }
    float inv = 1.f / l;
    #pragma unroll
    for (int e = 0; e < 4; ++e) {
        float x0 = v0[e] * inv; x0 = x0 > 0.f ? x0 : (__expf(x0) - 1.f);
        float x1 = v1[e] * inv; x1 = x1 > 0.f ? x1 : (__expf(x1) - 1.f);
        hu[row][cg * 8 + e] = x0;
        hu[row][cg * 8 + 4 + e] = x1;
    }
    __syncthreads();

    if (t < 16 * NCLS) {
        int rr = t / NCLS, cls = t - rr * NCLS;
        const f32x4* hurow = (const f32x4*)&hu[rr][0];
        const f32x4* wcrow = (const f32x4*)(Wc + cls * OUT_F);
        float sum = bcv[cls];
        #pragma unroll 8
        for (int c4 = 0; c4 < OUT_F / 4; ++c4) {
            f32x4 hv = hurow[c4];
            f32x4 wv = wcrow[c4];
            sum += hv[0] * wv[0] + hv[1] * wv[1] + hv[2] * wv[2] + hv[3] * wv[3];
        }
        out[(size_t)(i0 + rr) * NCLS + cls] = sum;
    }
}

// ---------------------------------------------------------------------------
extern "C" void kernel_launch(void* const* d_in, const int* in_sizes, int n_in,
                              void* d_out, int out_size, void* d_ws, size_t ws_size,
                              hipStream_t stream) {
    const float* h    = (const float*)d_in[0];
    const int*   dist = (const int*)d_in[1];
    const float* W    = (const float*)d_in[2];
    const float* a    = (const float*)d_in[3];
    const float* Wc   = (const float*)d_in[4];
    const float* bc   = (const float*)d_in[5];
    float* out = (float*)d_out;

    char* ws = (char*)d_ws;
    size_t off = 0;
    short* WhT  = (short*)(ws + off); off += (size_t)OUT_F * N * 2;     // 2 MB
    short* WThi = (short*)(ws + off); off += (size_t)IN_F * OUT_F * 2;  // 128 KB
    short* WTlo = (short*)(ws + off); off += (size_t)IN_F * OUT_F * 2;  // 128 KB
    float* Wh1  = (float*)(ws + off); off += (size_t)N * 4;
    float* Wh2  = (float*)(ws + off); off += (size_t)N * 4;
    unsigned char* mask8 = (unsigned char*)(ws + off); off += (size_t)N * (N / 8);  // 8 MB
    float* acc_part = (float*)(ws + off); off += (size_t)NSP * N * OUT_F * 4;       // 32 MB
    float* l_part   = (float*)(ws + off);                                            // 256 KB

    hipLaunchKernelGGL(pack_kernel, dim3(N / 4), dim3(256), 0, stream, dist, mask8);
    hipLaunchKernelGGL(split_w_kernel, dim3(256), dim3(256), 0, stream, W, WThi, WTlo);
    hipLaunchKernelGGL(wh_kernel, dim3(N / WH_ROWS), dim3(256), 0, stream,
                       h, WThi, WTlo, a, WhT, Wh1, Wh2);
    hipLaunchKernelGGL(attn_kernel, dim3(256 * NSP), dim3(256), 0, stream,
                       (const unsigned*)mask8, WhT, Wh1, Wh2, acc_part, l_part);
    hipLaunchKernelGGL(reduce_kernel, dim3(N / 16), dim3(256), 0, stream,
                       acc_part, l_part, Wc, bc, out);
}